// Round 9
// baseline (182.824 us; speedup 1.0000x reference)
//
#include <hip/hip_runtime.h>
#include <hip/hip_fp16.h>

#define VIEWS 16
#define NN 256
#define DWS 131                     // dwords per LDS row (262 halves: cols -2..259)
#define ROWS 259                    // rows y=-1..257 (index = y+1)
#define LDS_DW (ROWS*DWS)           // 33,929 dwords = 135,716 B

typedef __fp16 h2 __attribute__((ext_vector_type(2)));
typedef float  f2 __attribute__((ext_vector_type(2)));
union U32H2 { uint32_t u; h2 h; };

template<int CTRL>
__device__ __forceinline__ float dpp_add(float x) {
    int t = __builtin_amdgcn_update_dpp(0, __float_as_int(x), CTRL, 0xF, 0xF, true);
    return x + __int_as_float(t);
}

__device__ __forceinline__ float fract_f(float x) {
#if __has_builtin(__builtin_amdgcn_fractf)
    return __builtin_amdgcn_fractf(x);
#else
    return x - floorf(x);
#endif
}

__device__ __forceinline__ float wave_total(float p) {
    p = dpp_add<0xB1>(p);    // xor 1 (quad_perm)
    p = dpp_add<0x4E>(p);    // xor 2 (quad_perm)
    p = dpp_add<0x141>(p);   // row_half_mirror
    p = dpp_add<0x140>(p);   // row_mirror -> 16-lane row sums
    p = dpp_add<0x142>(p);   // row_bcast15
    p = dpp_add<0x143>(p);   // row_bcast31: lane63 = wave total
    return p;
}

// capture wave total (in lane 63 of p) into lane `i` of creg; i is wave-uniform
__device__ __forceinline__ float capture(float p, int i, float creg) {
    int tot = __builtin_amdgcn_readlane(__float_as_int(p), 63);
#if __has_builtin(__builtin_amdgcn_writelane)
    return __int_as_float(__builtin_amdgcn_writelane(tot, i, __float_as_int(creg)));
#else
    int lane = threadIdx.x & 63;
    return (lane == i) ? __int_as_float(tot) : creg;
#endif
}

// one bilinear tap at shifted coords (u,v); u in [1,258], v in [0,257] after clamp
__device__ __forceinline__ float tap(const uint32_t* lds, float u, float v) {
    u = fminf(fmaxf(u, 1.0f), 258.0f);     // -> v_med3
    v = fminf(fmaxf(v, 0.0f), 257.0f);
    int x0 = (int)u;
    int y0 = (int)v;
    float wx = fract_f(u);
    float wy = fract_f(v);
    h2 wxp = __builtin_amdgcn_cvt_pkrtz(1.0f - wx, wx);
    int d = (int)__umul24((unsigned)y0, 131u) + (x0 >> 1);
    uint32_t rA0 = lds[d];
    uint32_t rA1 = lds[d + 1];
    uint32_t rB0 = lds[d + DWS];
    uint32_t rB1 = lds[d + DWS + 1];
    uint32_t sh = (uint32_t)(x0 << 4);     // alignbit uses bits[4:0] = 16*(x0&1)
    U32H2 pa, pb;
    pa.u = __builtin_amdgcn_alignbit(rA1, rA0, sh);
    pb.u = __builtin_amdgcn_alignbit(rB1, rB0, sh);
    float a1 = __builtin_amdgcn_fdot2(wxp, pa.h, 0.0f, false);
    float a2 = __builtin_amdgcn_fdot2(wxp, pb.h, 0.0f, false);
    return fmaf(wy, a2 - a1, a1);
}

__launch_bounds__(1024, 1)
__global__ void fp_kernel(const float* __restrict__ vol, float* __restrict__ out) {
    __shared__ uint32_t lds[LDS_DW];
    const int tid = threadIdx.x;
    const int z = blockIdx.x;

    // ---- zero LDS (borders must be 0) ----
    for (int i = tid; i < LDS_DW; i += 1024) lds[i] = 0u;
    __syncthreads();

    // ---- stage slice z as fp16 (dword = 2 adjacent-x halves) ----
    __half* ldsH = (__half*)lds;
    const float* sp = vol + (size_t)z * (NN * NN);
    #pragma unroll
    for (int i = 0; i < 16; ++i) {
        int e = i * 4096 + tid * 4;
        float4 v4 = *(const float4*)(sp + e);
        int row = (e >> 8) + 1;
        int col = (e & 255) + 2;               // even -> dword-aligned
        __half2* p = (__half2*)&ldsH[row * (2 * DWS) + col];
        p[0] = __halves2half2(__float2half_rn(v4.x), __float2half_rn(v4.y));
        p[1] = __halves2half2(__float2half_rn(v4.z), __float2half_rn(v4.w));
    }
    __syncthreads();

    // ---- 90-degree view pairing: wave -> (pair k, march-half h) ----
    // proj_k[y]  = sum over x of field S_k(x,y)          (register accumulate)
    // proj_k8[y] = column sum of S_k at x = 255-y        (per-step wave reduce)
    const int wave = tid >> 6;
    const int lane = tid & 63;
    const int k = wave >> 1;
    const int h = wave & 1;
    const float ang = 0.017453292519943295f + (float)k * 0.19634954084936207f;
    const float c = cosf(ang), s = sinf(ang);

    // shifted coords: u = ix + 2 in [1,258], v = iy + 1 in [0,257]
    // u = c*(x+.5) - s*(y+.5) + 128(1-c+s) + 1.5 ; v = s*(x+.5) + c*(y+.5) + 128(1-s-c) + .5
    f2 bu01, bu23, bv01, bv23;
    float acc[4];
    {
        const float Cu = 128.0f * (1.0f - c + s) + 1.5f + 0.5f * c;
        const float Cv = 128.0f * (1.0f - s - c) + 0.5f + 0.5f * s;
        float p0 = (float)lane + 0.5f;
        bu01 = (f2){ fmaf(-s, p0, Cu),          fmaf(-s, p0 + 64.f, Cu) };
        bu23 = (f2){ fmaf(-s, p0 + 128.f, Cu),  fmaf(-s, p0 + 192.f, Cu) };
        bv01 = (f2){ fmaf( c, p0, Cv),          fmaf( c, p0 + 64.f, Cv) };
        bv23 = (f2){ fmaf( c, p0 + 128.f, Cv),  fmaf( c, p0 + 192.f, Cv) };
        acc[0] = acc[1] = acc[2] = acc[3] = 0.f;
    }
    const f2 c2 = (f2){c, c};
    const f2 s2 = (f2){s, s};

    float creg0 = 0.0f, creg1 = 0.0f;   // column totals at steps 128h+i, 128h+64+i
    float tfa = (float)(128 * h);
    #pragma unroll 2
    for (int i = 0; i < 64; ++i) {
        const f2 ta2 = (f2){tfa, tfa};
        const f2 tb2 = (f2){tfa + 64.f, tfa + 64.f};
        // packed coordinate gen (v_pk_fma_f32 if backend supports; else 2x fma)
        f2 uA01 = __builtin_elementwise_fma(c2, ta2, bu01);
        f2 uA23 = __builtin_elementwise_fma(c2, ta2, bu23);
        f2 vA01 = __builtin_elementwise_fma(s2, ta2, bv01);
        f2 vA23 = __builtin_elementwise_fma(s2, ta2, bv23);
        f2 uB01 = __builtin_elementwise_fma(c2, tb2, bu01);
        f2 uB23 = __builtin_elementwise_fma(c2, tb2, bu23);
        f2 vB01 = __builtin_elementwise_fma(s2, tb2, bv01);
        f2 vB23 = __builtin_elementwise_fma(s2, tb2, bv23);

        float ta0 = tap(lds, uA01.x, vA01.x);
        float ta1 = tap(lds, uA01.y, vA01.y);
        float ta2_ = tap(lds, uA23.x, vA23.x);
        float ta3 = tap(lds, uA23.y, vA23.y);
        float tb0 = tap(lds, uB01.x, vB01.x);
        float tb1 = tap(lds, uB01.y, vB01.y);
        float tb2_ = tap(lds, uB23.x, vB23.x);
        float tb3 = tap(lds, uB23.y, vB23.y);

        acc[0] += ta0 + tb0;
        acc[1] += ta1 + tb1;
        acc[2] += ta2_ + tb2_;
        acc[3] += ta3 + tb3;

        float pa_ = (ta0 + ta1) + (ta2_ + ta3);
        float pb_ = (tb0 + tb1) + (tb2_ + tb3);
        pa_ = wave_total(pa_);
        pb_ = wave_total(pb_);
        creg0 = capture(pa_, i, creg0);
        creg1 = capture(pb_, i, creg1);
        tfa += 1.0f;
    }

    __syncthreads();   // all taps done; safe to reuse LDS

    // ---- assemble [256 y][16 views] in LDS ----
    float* lout = (float*)lds;   // 4096 floats
    {   // column results -> view k+8, y = 255 - x  (disjoint x-ranges per h)
        int ybase = 255 - 128 * h;
        lout[(ybase - lane) * VIEWS + (k + 8)] = creg0;
        lout[(ybase - 64 - lane) * VIEWS + (k + 8)] = creg1;
    }
    if (h == 0) {
        #pragma unroll
        for (int r = 0; r < 4; ++r)
            lout[(lane + 64 * r) * VIEWS + k] = acc[r];
    }
    __syncthreads();
    if (h == 1) {
        #pragma unroll
        for (int r = 0; r < 4; ++r)
            lout[(lane + 64 * r) * VIEWS + k] += acc[r];
    }
    __syncthreads();

    float4 v4 = *(float4*)&lout[tid * 4];
    float4* o4 = (float4*)(out + (size_t)z * (NN * VIEWS));
    o4[tid] = v4;
}

extern "C" void kernel_launch(void* const* d_in, const int* in_sizes, int n_in,
                              void* d_out, int out_size, void* d_ws, size_t ws_size,
                              hipStream_t stream) {
    const float* vol = (const float*)d_in[0];
    float* out = (float*)d_out;
    fp_kernel<<<NN, 1024, 0, stream>>>(vol, out);
}

// Round 12
// 179.718 us; speedup vs baseline: 1.0173x; 1.0173x over previous
//
#include <hip/hip_runtime.h>
#include <hip/hip_fp16.h>

#define VIEWS 16
#define NN 256
#define DWS 131                     // dwords per LDS row (262 halves: cols -2..259)
#define ROWS 259                    // rows y=-1..257 (index = y+1)
#define LDS_DW (ROWS*DWS)           // 33,929 dwords = 135,716 B

typedef __fp16 h2 __attribute__((ext_vector_type(2)));
union U32H2 { uint32_t u; h2 h; };

template<int CTRL>
__device__ __forceinline__ float dpp_add(float x) {
    int t = __builtin_amdgcn_update_dpp(0, __float_as_int(x), CTRL, 0xF, 0xF, true);
    return x + __int_as_float(t);
}

__device__ __forceinline__ float fract_f(float x) {
#if __has_builtin(__builtin_amdgcn_fractf)
    return __builtin_amdgcn_fractf(x);
#else
    return x - floorf(x);
#endif
}

// one march-step: 4 taps (r=0..3), accumulate per-lane row sums into acc[],
// produce the 4-tap partial for the cross-lane column reduction
#define DO_STEP(PARTIAL) do {                                                  \
    PARTIAL = 0.f;                                                             \
    _Pragma("unroll")                                                          \
    for (int r = 0; r < 4; ++r) {                                              \
        float u = fmaf(c, xf, bix[r]);                                         \
        float v = fmaf(s, xf, biy[r]);                                         \
        u = fminf(fmaxf(u, 1.0f), 258.0f);   /* -> v_med3 */                   \
        v = fminf(fmaxf(v, 0.0f), 257.0f);                                     \
        int x0 = (int)u;                                                       \
        int y0 = (int)v;                                                       \
        float wx = fract_f(u);                                                 \
        float wy = fract_f(v);                                                 \
        h2 wxp = __builtin_amdgcn_cvt_pkrtz(1.0f - wx, wx);                    \
        int d = (int)__umul24((unsigned)y0, 131u) + (x0 >> 1);                 \
        uint32_t rA0 = lds[d];                                                 \
        uint32_t rA1 = lds[d + 1];                                             \
        uint32_t rB0 = lds[d + DWS];                                           \
        uint32_t rB1 = lds[d + DWS + 1];                                       \
        uint32_t sh = (uint32_t)(x0 << 4);   /* alignbit uses bits[4:0] */     \
        U32H2 pa, pb;                                                          \
        pa.u = __builtin_amdgcn_alignbit(rA1, rA0, sh);                        \
        pb.u = __builtin_amdgcn_alignbit(rB1, rB0, sh);                        \
        float a1 = __builtin_amdgcn_fdot2(wxp, pa.h, 0.0f, false);             \
        float a2 = __builtin_amdgcn_fdot2(wxp, pb.h, 0.0f, false);             \
        float t = fmaf(wy, a2 - a1, a1);                                       \
        acc[r] += t;                                                           \
        PARTIAL += t;                                                          \
    }                                                                          \
    xf += 1.0f;                                                                \
} while (0)

#define BUTTERFLY(P) do {                                                      \
    P = dpp_add<0xB1>(P);    /* xor 1  */                                      \
    P = dpp_add<0x4E>(P);    /* xor 2  */                                      \
    P = dpp_add<0x141>(P);   /* row_half_mirror */                             \
    P = dpp_add<0x140>(P);   /* row_mirror */                                  \
    P = dpp_add<0x142>(P);   /* row_bcast15 */                                 \
    P = dpp_add<0x143>(P);   /* row_bcast31: lane63 = total */                 \
} while (0)

__launch_bounds__(1024, 1)
__global__ void fp_kernel(const float* __restrict__ vol, float* __restrict__ out) {
    __shared__ uint32_t lds[LDS_DW];
    const int tid = threadIdx.x;
    const int z = blockIdx.x;

    // ---- zero LDS (borders must be 0) ----
    for (int i = tid; i < LDS_DW; i += 1024) lds[i] = 0u;
    __syncthreads();

    // ---- stage slice z as fp16 (dword = 2 adjacent-x halves) ----
    __half* ldsH = (__half*)lds;
    const float* sp = vol + (size_t)z * (NN * NN);
    #pragma unroll
    for (int i = 0; i < 16; ++i) {
        int e = i * 4096 + tid * 4;
        float4 v4 = *(const float4*)(sp + e);
        int row = (e >> 8) + 1;
        int col = (e & 255) + 2;               // even -> dword-aligned
        __half2* p = (__half2*)&ldsH[row * (2 * DWS) + col];
        p[0] = __halves2half2(__float2half_rn(v4.x), __float2half_rn(v4.y));
        p[1] = __halves2half2(__float2half_rn(v4.z), __float2half_rn(v4.w));
    }
    __syncthreads();

    // ---- 90-degree view pairing: wave -> (pair k, march-half h) ----
    // proj_k[y]  = sum over x of field S_k(x,y)      (register accumulate)
    // proj_k8[y] = column sum of S_k at x = 255-y    (per-step wave reduce)
    const int wave = tid >> 6;
    const int lane = tid & 63;
    const int k = wave >> 1;
    const int h = wave & 1;
    const float ang = 0.017453292519943295f + (float)k * 0.19634954084936207f;
    const float c = cosf(ang), s = sinf(ang);

    // shifted coords: u = ix + 2 in [1,258], v = iy + 1 in [0,257]
    float bix[4], biy[4], acc[4];
    #pragma unroll
    for (int r = 0; r < 4; ++r) {
        float py = (float)(lane + 64 * r) + 0.5f;
        bix[r] = -s * py + 128.0f * (1.0f - c + s) + 1.5f + 0.5f * c;
        biy[r] =  c * py + 128.0f * (1.0f - s - c) + 0.5f + 0.5f * s;
        acc[r] = 0.0f;
    }
    float xf = (float)(128 * h);   // march variable

    float creg0 = 0.0f, creg1 = 0.0f;   // column totals at steps 128h+i, 128h+64+i
    #pragma unroll 2
    for (int i = 0; i < 64; ++i) {
        float partial; DO_STEP(partial);
        BUTTERFLY(partial);
        float tot = __int_as_float(__builtin_amdgcn_readlane(__float_as_int(partial), 63));
        creg0 = (lane == i) ? tot : creg0;
    }
    #pragma unroll 2
    for (int i = 0; i < 64; ++i) {
        float partial; DO_STEP(partial);
        BUTTERFLY(partial);
        float tot = __int_as_float(__builtin_amdgcn_readlane(__float_as_int(partial), 63));
        creg1 = (lane == i) ? tot : creg1;
    }

    __syncthreads();   // all taps done; safe to reuse LDS

    // ---- assemble [256 y][16 views] in LDS ----
    float* lout = (float*)lds;   // 4096 floats
    {   // column results -> view k+8, y = 255 - x  (disjoint x-ranges per h)
        int ybase = 255 - 128 * h;
        lout[(ybase - lane) * VIEWS + (k + 8)] = creg0;
        lout[(ybase - 64 - lane) * VIEWS + (k + 8)] = creg1;
    }
    if (h == 0) {
        #pragma unroll
        for (int r = 0; r < 4; ++r)
            lout[(lane + 64 * r) * VIEWS + k] = acc[r];
    }
    __syncthreads();
    if (h == 1) {
        #pragma unroll
        for (int r = 0; r < 4; ++r)
            lout[(lane + 64 * r) * VIEWS + k] += acc[r];
    }
    __syncthreads();

    float4 v4 = *(float4*)&lout[tid * 4];
    float4* o4 = (float4*)(out + (size_t)z * (NN * VIEWS));
    o4[tid] = v4;
}

extern "C" void kernel_launch(void* const* d_in, const int* in_sizes, int n_in,
                              void* d_out, int out_size, void* d_ws, size_t ws_size,
                              hipStream_t stream) {
    const float* vol = (const float*)d_in[0];
    float* out = (float*)d_out;
    fp_kernel<<<NN, 1024, 0, stream>>>(vol, out);
}